// Round 2
// baseline (1173.086 us; speedup 1.0000x reference)
//
#include <hip/hip_runtime.h>
#include <math.h>

// Problem constants (from reference)
#define BATCH 128
#define NI    1152
#define ND    8
#define NC    32
#define NE    16
#define NROUT 3

// Tiling: thread = (b_local, c); block = 8 batches x 32 capsules; no LDS.
#define NTHREADS 256
#define BT       8                 // batches per block = NTHREADS / NC
#define ISPLIT   64                // blocks along i
#define ICHUNK   (NI / ISPLIT)     // 18

// Fused routing-iteration kernel (no LDS, no __syncthreads):
//  - recomputes u_hat[b,i,c,:] from x (broadcast load) and W (L1/L2-served)
//  - logits via dot(u_hat, o_sum); softmax over c = 32-lane shfl reduce
//  - accumulates s[b,c,e] in registers, one atomicAdd per (thread,e) at end
__global__ __launch_bounds__(NTHREADS, 4)
void route_iter_kernel(const float* __restrict__ x, const float* __restrict__ W,
                       const float* __restrict__ o_sum, float* __restrict__ s_out,
                       int iter)
{
    const int tid = threadIdx.x;
    const int c   = tid & 31;          // capsule (lanes 0..31 of each half-wave)
    const int b_l = tid >> 5;          // batch within tile
    const int ic  = blockIdx.x;        // i-chunk
    const int bt  = blockIdx.y;        // batch tile
    const int b   = bt * BT + b_l;
    const int i0  = ic * ICHUNK;

    // o_sum[b,c,:] in registers (only needed for iter > 0)
    float o_reg[NE];
    if (iter > 0) {
        const float4* op = (const float4*)(o_sum + ((size_t)b * NC + c) * NE);
#pragma unroll
        for (int e4 = 0; e4 < 4; ++e4) {
            float4 v = op[e4];
            o_reg[e4*4+0] = v.x; o_reg[e4*4+1] = v.y;
            o_reg[e4*4+2] = v.z; o_reg[e4*4+3] = v.w;
        }
    }

    float s_acc[NE];
#pragma unroll
    for (int e = 0; e < NE; ++e) s_acc[e] = 0.f;

    for (int ii = 0; ii < ICHUNK; ++ii) {
        const int i = i0 + ii;

        // x[b,i,:] — same address across the 32 lanes of a c-group: broadcast
        const float* xp = x + ((size_t)b * NI + i) * ND;
        float4 xa = *(const float4*)xp;
        float4 xb = *((const float4*)xp + 1);
        float xv[ND] = {xa.x, xa.y, xa.z, xa.w, xb.x, xb.y, xb.z, xb.w};

        // u_hat[b,i,c,:]: W[i,c,:,:] is 128 consecutive floats per lane
        const float4* wp = (const float4*)(W + ((size_t)i * NC + c) * (ND * NE));
        float uh[NE];
#pragma unroll
        for (int e = 0; e < NE; ++e) uh[e] = 0.f;
#pragma unroll
        for (int d = 0; d < ND; ++d) {
            float4 w0 = wp[d*4+0];
            float4 w1 = wp[d*4+1];
            float4 w2 = wp[d*4+2];
            float4 w3 = wp[d*4+3];
            float xd = xv[d];
            uh[0]  = fmaf(xd, w0.x, uh[0]);
            uh[1]  = fmaf(xd, w0.y, uh[1]);
            uh[2]  = fmaf(xd, w0.z, uh[2]);
            uh[3]  = fmaf(xd, w0.w, uh[3]);
            uh[4]  = fmaf(xd, w1.x, uh[4]);
            uh[5]  = fmaf(xd, w1.y, uh[5]);
            uh[6]  = fmaf(xd, w1.z, uh[6]);
            uh[7]  = fmaf(xd, w1.w, uh[7]);
            uh[8]  = fmaf(xd, w2.x, uh[8]);
            uh[9]  = fmaf(xd, w2.y, uh[9]);
            uh[10] = fmaf(xd, w2.z, uh[10]);
            uh[11] = fmaf(xd, w2.w, uh[11]);
            uh[12] = fmaf(xd, w3.x, uh[12]);
            uh[13] = fmaf(xd, w3.y, uh[13]);
            uh[14] = fmaf(xd, w3.z, uh[14]);
            uh[15] = fmaf(xd, w3.w, uh[15]);
        }

        // routing weight
        float wgt;
        if (iter > 0) {
            float lg = 0.f;
#pragma unroll
            for (int e = 0; e < NE; ++e) lg = fmaf(uh[e], o_reg[e], lg);
            // |logit| small by construction -> no max subtraction needed
            float el = __expf(lg);
            float denom = el;
            denom += __shfl_xor(denom, 1, 32);
            denom += __shfl_xor(denom, 2, 32);
            denom += __shfl_xor(denom, 4, 32);
            denom += __shfl_xor(denom, 8, 32);
            denom += __shfl_xor(denom, 16, 32);
            wgt = el / denom;
        } else {
            wgt = 1.f / 32.f;
        }

#pragma unroll
        for (int e = 0; e < NE; ++e) s_acc[e] = fmaf(wgt, uh[e], s_acc[e]);
    }

    // reduce partials across i-chunk blocks
    float* dst = s_out + ((size_t)b * NC + c) * NE;
#pragma unroll
    for (int e = 0; e < NE; ++e) atomicAdd(dst + e, s_acc[e]);
}

// squash(s) and update o_sum (or write final output)
__global__ __launch_bounds__(NTHREADS)
void squash_kernel(const float* __restrict__ s_in, float* __restrict__ o_sum,
                   float* __restrict__ out, int last)
{
    const int b  = blockIdx.x;
    const int t  = threadIdx.x;
    const int c0 = t >> 4;
    const int e  = t & 15;

#pragma unroll
    for (int cj = 0; cj < 2; ++cj) {
        const int c   = c0 + cj * 16;
        const int idx = b * (NC * NE) + c * NE + e;
        float v = s_in[idx];
        float q = v * v;
        q += __shfl_xor(q, 1, 16);
        q += __shfl_xor(q, 2, 16);
        q += __shfl_xor(q, 4, 16);
        q += __shfl_xor(q, 8, 16);
        // scale = s2/(1+s2)/sqrt(s2) == sqrt(s2)/(1+s2)
        float scale = sqrtf(q) / (1.f + q);
        float o = scale * v;
        if (last) out[idx]     = o;
        else      o_sum[idx]  += o;
    }
}

extern "C" void kernel_launch(void* const* d_in, const int* in_sizes, int n_in,
                              void* d_out, int out_size, void* d_ws, size_t ws_size,
                              hipStream_t stream) {
    const float* x = (const float*)d_in[0];   // [128,1152,8]
    const float* W = (const float*)d_in[1];   // [1152,32,8,16]
    float* out = (float*)d_out;               // [128,32,16]

    float* s_buf = (float*)d_ws;              // 65536 floats
    float* o_sum = s_buf + BATCH * NC * NE;   // 65536 floats

    hipMemsetAsync(o_sum, 0, (size_t)BATCH * NC * NE * sizeof(float), stream);

    for (int it = 0; it < NROUT; ++it) {
        hipMemsetAsync(s_buf, 0, (size_t)BATCH * NC * NE * sizeof(float), stream);
        route_iter_kernel<<<dim3(ISPLIT, BATCH / BT), NTHREADS, 0, stream>>>(
            x, W, o_sum, s_buf, it);
        squash_kernel<<<BATCH, NTHREADS, 0, stream>>>(
            s_buf, o_sum, out, it == NROUT - 1 ? 1 : 0);
    }
}

// Round 3
// 242.548 us; speedup vs baseline: 4.8365x; 4.8365x over previous
//
#include <hip/hip_runtime.h>
#include <math.h>

// Problem constants (from reference)
#define BATCH 128
#define NI    1152
#define ND    8
#define NC    32
#define NE    16
#define NROUT 3

// Tiling
#define ISPLIT   64
#define ICHUNK   (NI / ISPLIT)   // 18
#define BT       16              // batches per block (each thread does 2)
#define RT_THREADS 256           // 32 c  x  8 batch-pairs
#define WROW     132             // padded words per W row (128 data + 4 pad)
#define SQ_THREADS 512

// ---------------------------------------------------------------------------
// route kernel: recompute u_hat from x,W (W double-buffered in LDS),
// softmax over c via 32-lane shfl, accumulate s in regs, write partial
// s-tile to a per-(ic) slice (no atomics) or atomicAdd fallback.
// ---------------------------------------------------------------------------
__global__ __launch_bounds__(RT_THREADS, 2)
void route_iter_kernel(const float* __restrict__ x, const float* __restrict__ W,
                       const float* __restrict__ o_sum, float* __restrict__ s_part,
                       int iter, int nslice, int use_atomic)
{
    __shared__ float Ws[2][NC * WROW];   // 2 x 16.9 KB

    const int tid = threadIdx.x;
    const int c   = tid & 31;            // capsule
    const int bp  = tid >> 5;            // 0..7 batch-pair id
    const int ic  = blockIdx.x;
    const int bt  = blockIdx.y;
    const int i0  = ic * ICHUNK;
    const int b0  = bt * BT + bp;        // batches b0 and b0+8

    // o_sum rows in registers (iter > 0 only)
    float o_reg[2][NE];
    if (iter > 0) {
#pragma unroll
        for (int bj = 0; bj < 2; ++bj) {
            const float4* op = (const float4*)(o_sum + ((size_t)(b0 + 8*bj) * NC + c) * NE);
#pragma unroll
            for (int q = 0; q < 4; ++q) {
                float4 v = op[q];
                o_reg[bj][q*4+0] = v.x; o_reg[bj][q*4+1] = v.y;
                o_reg[bj][q*4+2] = v.z; o_reg[bj][q*4+3] = v.w;
            }
        }
    }

    float s_acc[2][NE];
#pragma unroll
    for (int bj = 0; bj < 2; ++bj)
#pragma unroll
        for (int e = 0; e < NE; ++e) s_acc[bj][e] = 0.f;

    // ---- prologue: stage W[i0] into buf 0 (reg round-trip, padded dest) ----
    float4 pr[4];
    {
        const float4* src = (const float4*)(W + (size_t)i0 * (NC * ND * NE));
#pragma unroll
        for (int r = 0; r < 4; ++r) pr[r] = src[tid + r * RT_THREADS];
#pragma unroll
        for (int r = 0; r < 4; ++r) {
            int j = tid + r * RT_THREADS;            // float4 chunk 0..1023
            *(float4*)&Ws[0][(j >> 5) * WROW + (j & 31) * 4] = pr[r];
        }
    }

    for (int ii = 0; ii < ICHUNK; ++ii) {
        const int i = i0 + ii;

        // issue next-tile W loads early (hide under barrier + compute)
        if (ii + 1 < ICHUNK) {
            const float4* src = (const float4*)(W + (size_t)(i + 1) * (NC * ND * NE));
#pragma unroll
            for (int r = 0; r < 4; ++r) pr[r] = src[tid + r * RT_THREADS];
        }
        // x rows for both batches (32 c-lanes share the address: broadcast)
        const float* xp0 = x + ((size_t)b0 * NI + i) * ND;
        const float* xp1 = x + ((size_t)(b0 + 8) * NI + i) * ND;
        float4 xa0 = *(const float4*)xp0, xb0 = *((const float4*)xp0 + 1);
        float4 xa1 = *(const float4*)xp1, xb1 = *((const float4*)xp1 + 1);
        float xv0[ND] = {xa0.x, xa0.y, xa0.z, xa0.w, xb0.x, xb0.y, xb0.z, xb0.w};
        float xv1[ND] = {xa1.x, xa1.y, xa1.z, xa1.w, xb1.x, xb1.y, xb1.z, xb1.w};

        __syncthreads();   // buf[ii&1] fully written; prev readers done

        // ---- u_hat for (b0, c) and (b0+8, c) sharing one W-row read ----
        const float* wr = &Ws[ii & 1][c * WROW];
        float uh0[NE], uh1[NE];
#pragma unroll
        for (int e = 0; e < NE; ++e) { uh0[e] = 0.f; uh1[e] = 0.f; }
#pragma unroll
        for (int d = 0; d < ND; ++d) {
            const float xd0 = xv0[d], xd1 = xv1[d];
#pragma unroll
            for (int q = 0; q < 4; ++q) {
                float4 w = *(const float4*)&wr[d * 16 + q * 4];
                uh0[q*4+0] = fmaf(xd0, w.x, uh0[q*4+0]);
                uh0[q*4+1] = fmaf(xd0, w.y, uh0[q*4+1]);
                uh0[q*4+2] = fmaf(xd0, w.z, uh0[q*4+2]);
                uh0[q*4+3] = fmaf(xd0, w.w, uh0[q*4+3]);
                uh1[q*4+0] = fmaf(xd1, w.x, uh1[q*4+0]);
                uh1[q*4+1] = fmaf(xd1, w.y, uh1[q*4+1]);
                uh1[q*4+2] = fmaf(xd1, w.z, uh1[q*4+2]);
                uh1[q*4+3] = fmaf(xd1, w.w, uh1[q*4+3]);
            }
        }

        // ---- routing weights ----
        float w0, w1;
        if (iter > 0) {
            float lg0 = 0.f, lg1 = 0.f;
#pragma unroll
            for (int e = 0; e < NE; ++e) {
                lg0 = fmaf(uh0[e], o_reg[0][e], lg0);
                lg1 = fmaf(uh1[e], o_reg[1][e], lg1);
            }
            float e0 = __expf(lg0), e1 = __expf(lg1);
            float d0 = e0, d1 = e1;
#pragma unroll
            for (int m = 1; m < 32; m <<= 1) {
                d0 += __shfl_xor(d0, m, 32);
                d1 += __shfl_xor(d1, m, 32);
            }
            w0 = e0 / d0;
            w1 = e1 / d1;
        } else {
            w0 = w1 = (1.f / 32.f);
        }

#pragma unroll
        for (int e = 0; e < NE; ++e) {
            s_acc[0][e] = fmaf(w0, uh0[e], s_acc[0][e]);
            s_acc[1][e] = fmaf(w1, uh1[e], s_acc[1][e]);
        }

        // ---- write next W tile into the other buffer ----
        if (ii + 1 < ICHUNK) {
#pragma unroll
            for (int r = 0; r < 4; ++r) {
                int j = tid + r * RT_THREADS;
                *(float4*)&Ws[(ii + 1) & 1][(j >> 5) * WROW + (j & 31) * 4] = pr[r];
            }
        }
    }

    // ---- write partial s ----
    const int slice = ic & (nslice - 1);
#pragma unroll
    for (int bj = 0; bj < 2; ++bj) {
        const int b = b0 + 8 * bj;
        float* base = s_part + (((size_t)slice * BATCH + b) * NC + c) * NE;
        if (use_atomic) {
#pragma unroll
            for (int e = 0; e < NE; ++e) atomicAdd(base + e, s_acc[bj][e]);
        } else {
#pragma unroll
            for (int q = 0; q < 4; ++q) {
                *(float4*)(base + q * 4) =
                    make_float4(s_acc[bj][q*4+0], s_acc[bj][q*4+1],
                                s_acc[bj][q*4+2], s_acc[bj][q*4+3]);
            }
        }
    }
}

// ---------------------------------------------------------------------------
// squash kernel: reduce slices, squash, update o_sum / write output.
// One block per batch element; thread t = (c = t>>4, e = t&15).
// ---------------------------------------------------------------------------
__global__ __launch_bounds__(SQ_THREADS)
void squash_kernel(float* __restrict__ s_part, float* __restrict__ o_sum,
                   float* __restrict__ out, int iter, int nslice, int use_atomic)
{
    const int b = blockIdx.x;
    const int t = threadIdx.x;           // 0..511 = c*16 + e

    float acc = 0.f;
    for (int k = 0; k < nslice; ++k) {
        float* p = s_part + ((size_t)k * BATCH + b) * (NC * NE) + t;
        acc += *p;
        if (use_atomic) *p = 0.f;        // re-zero for next iteration / next call
    }

    float q = acc * acc;
    q += __shfl_xor(q, 1, 16);
    q += __shfl_xor(q, 2, 16);
    q += __shfl_xor(q, 4, 16);
    q += __shfl_xor(q, 8, 16);
    // scale = s2/(1+s2)/sqrt(s2) == sqrt(s2)/(1+s2)
    float scale = sqrtf(q) / (1.f + q);
    float o = scale * acc;

    const int idx = b * (NC * NE) + t;
    if (iter == NROUT - 1)      out[idx]   = o;
    else if (iter == 0)         o_sum[idx] = o;
    else                        o_sum[idx] += o;
}

extern "C" void kernel_launch(void* const* d_in, const int* in_sizes, int n_in,
                              void* d_out, int out_size, void* d_ws, size_t ws_size,
                              hipStream_t stream) {
    const float* x = (const float*)d_in[0];   // [128,1152,8]
    const float* W = (const float*)d_in[1];   // [1152,32,8,16]
    float* out = (float*)d_out;               // [128,32,16]

    float* o_sum  = (float*)d_ws;                       // 256 KB
    float* s_part = o_sum + (size_t)BATCH * NC * NE;    // nslice * 256 KB

    const size_t slice_bytes = (size_t)BATCH * NC * NE * sizeof(float);
    int nslice, use_atomic;
    if (ws_size >= slice_bytes * (64 + 1))      { nslice = 64; use_atomic = 0; }
    else if (ws_size >= slice_bytes * (8 + 1))  { nslice = 8;  use_atomic = 1; }
    else                                        { nslice = 1;  use_atomic = 1; }

    if (use_atomic)
        hipMemsetAsync(s_part, 0, slice_bytes * nslice, stream);

    for (int it = 0; it < NROUT; ++it) {
        route_iter_kernel<<<dim3(ISPLIT, BATCH / BT), RT_THREADS, 0, stream>>>(
            x, W, o_sum, s_part, it, nslice, use_atomic);
        squash_kernel<<<BATCH, SQ_THREADS, 0, stream>>>(
            s_part, o_sum, out, it, nslice, use_atomic);
    }
}

// Round 4
// 174.333 us; speedup vs baseline: 6.7290x; 1.3913x over previous
//
#include <hip/hip_runtime.h>
#include <math.h>

// Problem constants (from reference)
#define BATCH 128
#define NI    1152
#define ND    8
#define NC    32
#define NE    16
#define NROUT 3

// Tiling: thread = (c, eh, bp). 32 c x 2 e-halves x 4 batch-groups = 256.
// Each thread: 4 batches, 8 e's  ->  one ds_read_b128 feeds 16 FMAs.
#define ISPLIT     96
#define ICHUNK     (NI / ISPLIT)    // 12
#define BT         16
#define NB         4                // batches per thread
#define RT_THREADS 256
#define WROW       132              // padded row stride (4 mod 32 -> bank-uniform b128)
#define SQ_THREADS 256

template<int CTRL>
__device__ __forceinline__ float dpp_add(float v) {
    int t = __builtin_amdgcn_update_dpp(0, __float_as_int(v), CTRL, 0xF, 0xF, true);
    return v + __int_as_float(t);
}

// Sum over lane bits 0..4 (the 32 'c' lanes of each eh-half).
// xor1/xor2 via quad_perm; xor4 = row_half_mirror (quads already uniform);
// xor8 = row_mirror (octets uniform); xor16 via ds_swizzle.
__device__ __forceinline__ float sum_over_c(float v) {
    v = dpp_add<0xB1>(v);    // lane ^ 1   quad_perm(1,0,3,2)
    v = dpp_add<0x4E>(v);    // lane ^ 2   quad_perm(2,3,0,1)
    v = dpp_add<0x141>(v);   // lane ^ 4   row_half_mirror
    v = dpp_add<0x140>(v);   // lane ^ 8   row_mirror
    int s = __builtin_amdgcn_ds_swizzle(__float_as_int(v), 0x401F); // lane ^ 16
    return v + __int_as_float(s);
}

// Sum over lane bits 0..3 (16 e-lanes) for squash.
__device__ __forceinline__ float sum_over_e16(float v) {
    v = dpp_add<0xB1>(v);
    v = dpp_add<0x4E>(v);
    v = dpp_add<0x141>(v);
    v = dpp_add<0x140>(v);
    return v;
}

// ---------------------------------------------------------------------------
// Fused routing iteration. W double-buffered in LDS (reg round-trip, padded,
// conflict-free). x via wave-uniform (scalar) loads. Softmax over c fully
// in-wave: DPP + 1 swizzle + 1 shfl. Partial s written plain (nslice=ISPLIT)
// or atomically (fallback).
// ---------------------------------------------------------------------------
__global__ __launch_bounds__(RT_THREADS, 3)
void route_iter_kernel(const float* __restrict__ x, const float* __restrict__ W,
                       const float* __restrict__ o_sum, float* __restrict__ s_part,
                       int iter, int nslice, int use_atomic)
{
    __shared__ float Ws[2][NC * WROW];   // 2 x 16.9 KB

    const int tid = threadIdx.x;
    const int c   = tid & 31;
    const int eh  = (tid >> 5) & 1;
    const int bp  = __builtin_amdgcn_readfirstlane(tid >> 6);  // wave-uniform
    const int ic  = blockIdx.x;
    const int bt  = blockIdx.y;
    const int i0  = ic * ICHUNK;
    const int b0  = bt * BT + bp * NB;   // 4 consecutive batches per wave
    const int e0  = eh * 8;

    // o_sum[b, c, e0..e0+7] in registers (iter > 0 only)
    float o_reg[NB][8];
    if (iter > 0) {
#pragma unroll
        for (int j = 0; j < NB; ++j) {
            const float4* op = (const float4*)(o_sum + ((size_t)(b0 + j) * NC + c) * NE + e0);
            float4 a = op[0], b = op[1];
            o_reg[j][0] = a.x; o_reg[j][1] = a.y; o_reg[j][2] = a.z; o_reg[j][3] = a.w;
            o_reg[j][4] = b.x; o_reg[j][5] = b.y; o_reg[j][6] = b.z; o_reg[j][7] = b.w;
        }
    }

    float s_acc[NB][8];
#pragma unroll
    for (int j = 0; j < NB; ++j)
#pragma unroll
        for (int e = 0; e < 8; ++e) s_acc[j][e] = 0.f;

    // ---- prologue: stage W[i0] into buffer 0 ----
    float4 pr[4];
    {
        const float4* src = (const float4*)(W + (size_t)i0 * (NC * ND * NE));
#pragma unroll
        for (int r = 0; r < 4; ++r) pr[r] = src[tid + r * RT_THREADS];
#pragma unroll
        for (int r = 0; r < 4; ++r) {
            int j = tid + r * RT_THREADS;
            *(float4*)&Ws[0][(j >> 5) * WROW + (j & 31) * 4] = pr[r];
        }
    }

    for (int ii = 0; ii < ICHUNK; ++ii) {
        const int i = i0 + ii;

        // prefetch next W tile into registers (lands after compute)
        if (ii + 1 < ICHUNK) {
            const float4* src = (const float4*)(W + (size_t)(i + 1) * (NC * ND * NE));
#pragma unroll
            for (int r = 0; r < 4; ++r) pr[r] = src[tid + r * RT_THREADS];
        }

        // x rows: wave-uniform address -> scalar loads
        float xv[NB][ND];
#pragma unroll
        for (int j = 0; j < NB; ++j) {
            const float* xp = x + ((size_t)(b0 + j) * NI + i) * ND;
            float4 xa = *(const float4*)xp;
            float4 xb = *((const float4*)xp + 1);
            xv[j][0] = xa.x; xv[j][1] = xa.y; xv[j][2] = xa.z; xv[j][3] = xa.w;
            xv[j][4] = xb.x; xv[j][5] = xb.y; xv[j][6] = xb.z; xv[j][7] = xb.w;
        }

        __syncthreads();   // buf[ii&1] ready; previous readers done

        // ---- u_hat[b0..b0+3, c, e0..e0+7] ----
        const float* wr = &Ws[ii & 1][c * WROW + e0];
        float uh[NB][8];
#pragma unroll
        for (int j = 0; j < NB; ++j)
#pragma unroll
            for (int e = 0; e < 8; ++e) uh[j][e] = 0.f;

#pragma unroll
        for (int d = 0; d < ND; ++d) {
            float4 wa = *(const float4*)(wr + d * 16);
            float4 wb = *(const float4*)(wr + d * 16 + 4);
#pragma unroll
            for (int j = 0; j < NB; ++j) {
                const float xd = xv[j][d];
                uh[j][0] = fmaf(xd, wa.x, uh[j][0]);
                uh[j][1] = fmaf(xd, wa.y, uh[j][1]);
                uh[j][2] = fmaf(xd, wa.z, uh[j][2]);
                uh[j][3] = fmaf(xd, wa.w, uh[j][3]);
                uh[j][4] = fmaf(xd, wb.x, uh[j][4]);
                uh[j][5] = fmaf(xd, wb.y, uh[j][5]);
                uh[j][6] = fmaf(xd, wb.z, uh[j][6]);
                uh[j][7] = fmaf(xd, wb.w, uh[j][7]);
            }
        }

        // ---- routing weights + s accumulation ----
        if (iter > 0) {
#pragma unroll
            for (int j = 0; j < NB; ++j) {
                float lp = 0.f;
#pragma unroll
                for (int e = 0; e < 8; ++e) lp = fmaf(uh[j][e], o_reg[j][e], lp);
                lp += __shfl_xor(lp, 32);          // combine e-halves -> full logit
                float el = __expf(lp);             // |logit| small; no max-sub
                float den = sum_over_c(el);        // softmax denominator over 32 c
                float wgt = el / den;
#pragma unroll
                for (int e = 0; e < 8; ++e) s_acc[j][e] = fmaf(wgt, uh[j][e], s_acc[j][e]);
            }
        } else {
            const float wgt = 1.f / 32.f;
#pragma unroll
            for (int j = 0; j < NB; ++j)
#pragma unroll
                for (int e = 0; e < 8; ++e) s_acc[j][e] = fmaf(wgt, uh[j][e], s_acc[j][e]);
        }

        // ---- write next W tile into the other buffer ----
        if (ii + 1 < ICHUNK) {
#pragma unroll
            for (int r = 0; r < 4; ++r) {
                int j = tid + r * RT_THREADS;
                *(float4*)&Ws[(ii + 1) & 1][(j >> 5) * WROW + (j & 31) * 4] = pr[r];
            }
        }
    }

    // ---- write partial s ----
    const int slice = use_atomic ? (ic & (nslice - 1)) : ic;
#pragma unroll
    for (int j = 0; j < NB; ++j) {
        float* base = s_part + (((size_t)slice * BATCH + (b0 + j)) * NC + c) * NE + e0;
        if (use_atomic) {
#pragma unroll
            for (int e = 0; e < 8; ++e) atomicAdd(base + e, s_acc[j][e]);
        } else {
            *(float4*)(base)     = make_float4(s_acc[j][0], s_acc[j][1], s_acc[j][2], s_acc[j][3]);
            *(float4*)(base + 4) = make_float4(s_acc[j][4], s_acc[j][5], s_acc[j][6], s_acc[j][7]);
        }
    }
}

// ---------------------------------------------------------------------------
// squash: reduce slices, squash, update o_sum / write output.
// One thread per output element; e-reduction via DPP (lane bits 0..3).
// ---------------------------------------------------------------------------
__global__ __launch_bounds__(SQ_THREADS)
void squash_kernel(float* __restrict__ s_part, float* __restrict__ o_sum,
                   float* __restrict__ out, int iter, int nslice, int zero_after)
{
    const int idx = blockIdx.x * SQ_THREADS + threadIdx.x;  // (b*32 + c)*16 + e

    float acc = 0.f;
#pragma unroll 4
    for (int k = 0; k < nslice; ++k) {
        float* p = s_part + (size_t)k * (BATCH * NC * NE) + idx;
        acc += *p;
        if (zero_after) *p = 0.f;
    }

    float q = sum_over_e16(acc * acc);
    // scale = s2/(1+s2)/sqrt(s2) == sqrt(s2)/(1+s2)
    float scale = sqrtf(q) / (1.f + q);
    float o = scale * acc;

    if (iter == NROUT - 1)      out[idx]   = o;
    else if (iter == 0)         o_sum[idx] = o;
    else                        o_sum[idx] += o;
}

extern "C" void kernel_launch(void* const* d_in, const int* in_sizes, int n_in,
                              void* d_out, int out_size, void* d_ws, size_t ws_size,
                              hipStream_t stream) {
    const float* x = (const float*)d_in[0];   // [128,1152,8]
    const float* W = (const float*)d_in[1];   // [1152,32,8,16]
    float* out = (float*)d_out;               // [128,32,16]

    const size_t slice_elems = (size_t)BATCH * NC * NE;   // 65536
    const size_t slice_bytes = slice_elems * sizeof(float);

    float* o_sum  = (float*)d_ws;
    float* s_part = o_sum + slice_elems;

    int nslice, use_atomic;
    if (ws_size >= slice_bytes * (ISPLIT + 1)) { nslice = ISPLIT; use_atomic = 0; }
    else if (ws_size >= slice_bytes * (32 + 1)) { nslice = 32; use_atomic = 1; }
    else if (ws_size >= slice_bytes * (8 + 1))  { nslice = 8;  use_atomic = 1; }
    else                                        { nslice = 1;  use_atomic = 1; }

    if (use_atomic)
        hipMemsetAsync(s_part, 0, slice_bytes * nslice, stream);

    for (int it = 0; it < NROUT; ++it) {
        route_iter_kernel<<<dim3(ISPLIT, BATCH / BT), RT_THREADS, 0, stream>>>(
            x, W, o_sum, s_part, it, nslice, use_atomic);
        squash_kernel<<<(BATCH * NC * NE) / SQ_THREADS, SQ_THREADS, 0, stream>>>(
            s_part, o_sum, out, it, nslice, use_atomic);
    }
}